// Round 2
// baseline (563.825 us; speedup 1.0000x reference)
//
#include <hip/hip_runtime.h>
#include <cstdint>
#include <cstddef>

// Problem constants
#define CIN   192
#define COUT  192
#define KCB   1024
#define HWSZ  4096            // 64*64
#define NPIX  32768           // 8*64*64
#define LOGIT_SCALE_F 13.856406460551018f

// q tile is stashed in the logit region of d_out, cols [832,1024) of each
// pixel's 1024-wide row. Block b reads its own rows' q in stage A before any
// of its logit writes; rows are disjoint across blocks; q_kernel precedes
// logit_kernel on the stream. This keeps d_ws usage to km/vm only (1.57 MB)
// — round-1 post-timing corruption was traced to assuming ws_size >= 26.7MB.
#define QCOL0 832

// ---------------------------------------------------------------------------
// JAX threefry2x32 (key = (0,42)), partitionable stream: bits(i) = o0 ^ o1 of
// threefry2x32((k1,k2), (hi32(i)=0, lo32(i)=i))  [validated: round-1 first
// call passed => gumbel stream is argmax-exact for all 32768 pixels]
// ---------------------------------------------------------------------------
__device__ __forceinline__ void threefry_0_42(uint32_t x0, uint32_t x1,
                                              uint32_t& o0, uint32_t& o1) {
  const uint32_t ks0 = 0u;
  const uint32_t ks1 = 42u;
  const uint32_t ks2 = 0x1BD11BDAu ^ 0u ^ 42u;
  x0 += ks0; x1 += ks1;
#define TFR(r) { x0 += x1; x1 = (x1 << (r)) | (x1 >> (32 - (r))); x1 ^= x0; }
  TFR(13) TFR(15) TFR(26) TFR(6)
  x0 += ks1; x1 += ks2 + 1u;
  TFR(17) TFR(29) TFR(16) TFR(24)
  x0 += ks2; x1 += ks0 + 2u;
  TFR(13) TFR(15) TFR(26) TFR(6)
  x0 += ks0; x1 += ks1 + 3u;
  TFR(17) TFR(29) TFR(16) TFR(24)
  x0 += ks1; x1 += ks2 + 4u;
  TFR(13) TFR(15) TFR(26) TFR(6)
  x0 += ks2; x1 += ks0 + 5u;
#undef TFR
  o0 = x0; o1 = x1;
}

__device__ __forceinline__ float gumbel_from_bits(uint32_t b) {
  // uniform(minval=tiny, maxval=1): u in [0,1) from top-23 bits; max with tiny.
  // Precise logf kept for BOTH logs: v_log_f32 fast path has poor relative
  // accuracy near u~1, exactly where the winning (largest) gumbels live.
  float u = __uint_as_float((b >> 9) | 0x3F800000u) - 1.0f;
  u = fmaxf(u, 1.17549435e-38f);
  return -logf(-logf(u));
}

// ---------------------------------------------------------------------------
// Kernel 1: k = codebook @ wk^T, v = codebook @ wv^T   [1024 x 192 each]
// ---------------------------------------------------------------------------
__global__ __launch_bounds__(192) void kv_kernel(
    const float* __restrict__ cb, const float* __restrict__ wk,
    const float* __restrict__ wv, float* __restrict__ km, float* __restrict__ vm) {
  __shared__ float4 row[48];
  const int j = blockIdx.x;
  const int o = threadIdx.x;
  if (o < 48) row[o] = reinterpret_cast<const float4*>(cb + (size_t)j * CIN)[o];
  __syncthreads();
  const float4* wkr = reinterpret_cast<const float4*>(wk + (size_t)o * CIN);
  const float4* wvr = reinterpret_cast<const float4*>(wv + (size_t)o * CIN);
  float sk = 0.f, sv = 0.f;
#pragma unroll 8
  for (int c = 0; c < 48; ++c) {
    float4 a = row[c];
    float4 b = wkr[c];
    float4 w = wvr[c];
    sk = fmaf(a.x, b.x, sk); sk = fmaf(a.y, b.y, sk);
    sk = fmaf(a.z, b.z, sk); sk = fmaf(a.w, b.w, sk);
    sv = fmaf(a.x, w.x, sv); sv = fmaf(a.y, w.y, sv);
    sv = fmaf(a.z, w.z, sv); sv = fmaf(a.w, w.w, sv);
  }
  km[(size_t)j * COUT + o] = sk;
  vm[(size_t)j * COUT + o] = sv;
}

// ---------------------------------------------------------------------------
// Kernel 2: q[p][o] = sum_c latent[n][c][hw] * wq[o][c]
// Output goes to logit[p*1024 + QCOL0 + o] (see note at QCOL0).
// GEMM accumulation order identical to round 1 (argmax near-tie safety).
// ---------------------------------------------------------------------------
__global__ __launch_bounds__(256) void q_kernel(
    const float* __restrict__ latent, const float* __restrict__ wq,
    float* __restrict__ logitq) {
  __shared__ float aT[16][68];  // [c][p]
  __shared__ float bT[16][68];  // [c][o]
  const int tid = threadIdx.x;
  const int p0 = blockIdx.x * 64;
  const int o0 = blockIdx.y * 64;
  const int n = p0 >> 12, hw0 = p0 & 4095;
  const float* lat = latent + (size_t)n * (CIN * HWSZ);
  const int tp = tid & 15, to = tid >> 4;
  float acc[4][4] = {};

  for (int c0 = 0; c0 < CIN; c0 += 16) {
    __syncthreads();
    {
      int px = tid & 63, cr = tid >> 6;
#pragma unroll
      for (int i = 0; i < 4; ++i) {
        int c = cr + i * 4;
        aT[c][px] = lat[(size_t)(c0 + c) * HWSZ + hw0 + px];
      }
      int tx = tid & 15, ty = tid >> 4;
#pragma unroll
      for (int i = 0; i < 4; ++i) {
        int o = ty * 4 + i;
        bT[tx][o] = wq[(size_t)(o0 + o) * CIN + c0 + tx];
      }
    }
    __syncthreads();
#pragma unroll
    for (int c = 0; c < 16; ++c) {
      float4 av = *reinterpret_cast<const float4*>(&aT[c][4 * tp]);
      float4 bv = *reinterpret_cast<const float4*>(&bT[c][4 * to]);
      acc[0][0] = fmaf(av.x, bv.x, acc[0][0]); acc[0][1] = fmaf(av.x, bv.y, acc[0][1]);
      acc[0][2] = fmaf(av.x, bv.z, acc[0][2]); acc[0][3] = fmaf(av.x, bv.w, acc[0][3]);
      acc[1][0] = fmaf(av.y, bv.x, acc[1][0]); acc[1][1] = fmaf(av.y, bv.y, acc[1][1]);
      acc[1][2] = fmaf(av.y, bv.z, acc[1][2]); acc[1][3] = fmaf(av.y, bv.w, acc[1][3]);
      acc[2][0] = fmaf(av.z, bv.x, acc[2][0]); acc[2][1] = fmaf(av.z, bv.y, acc[2][1]);
      acc[2][2] = fmaf(av.z, bv.z, acc[2][2]); acc[2][3] = fmaf(av.z, bv.w, acc[2][3]);
      acc[3][0] = fmaf(av.w, bv.x, acc[3][0]); acc[3][1] = fmaf(av.w, bv.y, acc[3][1]);
      acc[3][2] = fmaf(av.w, bv.z, acc[3][2]); acc[3][3] = fmaf(av.w, bv.w, acc[3][3]);
    }
  }
#pragma unroll
  for (int ii = 0; ii < 4; ++ii) {
    float4 w;
    w.x = acc[ii][0]; w.y = acc[ii][1]; w.z = acc[ii][2]; w.w = acc[ii][3];
    *reinterpret_cast<float4*>(logitq + (size_t)(p0 + 4 * tp + ii) * KCB + QCOL0 + o0 + 4 * to) = w;
  }
}

// ---------------------------------------------------------------------------
// Kernel 3 (fused): logit GEMM + gumbel + dual argmax + V gather.
// LDS trimmed to 63.75 KB (in-wave shfl reduce replaces 16KB arrays) so
// 2 blocks/CU are co-resident (round-1 theory: 77.8KB -> 1 block/CU was the
// 3.5x-vs-VALU-floor slowdown).
// ---------------------------------------------------------------------------
__global__ __launch_bounds__(256) void logit_kernel(
    const float* __restrict__ km, const float* __restrict__ vm,
    const float* __restrict__ t1p, float* __restrict__ logit_out,
    float* __restrict__ code_out, float* __restrict__ quant_out) {
  __shared__ float aT[CIN][68];   // [c][p] full-K resident: 52.2 KB
  __shared__ float bT[32][68];    // [c][j] chunk: 8.7 KB
  __shared__ float wLv[64][4];
  __shared__ int   wLi[64][4];
  __shared__ float wSv[64][4];
  __shared__ int   wSi[64][4];
  __shared__ int   sIdx[64];

  const int tid = threadIdx.x;
  const int p0 = blockIdx.x * 64;
  const float t1 = t1p[0];

  // stage A: q rows p0..p0+63 from logit[:, QCOL0:QCOL0+192], transposed
  for (int i = 0; i < 12; ++i) {
    int flat = tid + i * 256;           // 0..3071
    int r = flat / 48, c4 = flat % 48;  // row, float4-col
    float4 v = reinterpret_cast<const float4*>(
        logit_out + (size_t)(p0 + r) * KCB + QCOL0)[c4];
    aT[c4 * 4 + 0][r] = v.x;
    aT[c4 * 4 + 1][r] = v.y;
    aT[c4 * 4 + 2][r] = v.z;
    aT[c4 * 4 + 3][r] = v.w;
  }

  const int tp = tid & 15;  // pixel frag: rows 4tp..4tp+3
  const int to = tid >> 4;  // j frag within subtile: 4to..4to+3
  float Lv[4], Sv[4];
  int Li[4], Si[4];
#pragma unroll
  for (int ii = 0; ii < 4; ++ii) {
    Lv[ii] = -INFINITY; Sv[ii] = -INFINITY; Li[ii] = 0; Si[ii] = 0;
  }

  for (int jt = 0; jt < 16; ++jt) {
    float acc[4][4] = {};
    for (int c0 = 0; c0 < CIN; c0 += 32) {
      __syncthreads();  // protect bT (also orders aT staging on first pass)
      {
        int c4 = tid & 7, jj = tid >> 3;  // 8 float4-cols x 32 rows, 2 passes
#pragma unroll
        for (int pass = 0; pass < 2; ++pass) {
          int jloc = jj + pass * 32;
          int jg = jt * 64 + jloc;
          float4 v = reinterpret_cast<const float4*>(km + (size_t)jg * CIN + c0)[c4];
          bT[c4 * 4 + 0][jloc] = v.x;
          bT[c4 * 4 + 1][jloc] = v.y;
          bT[c4 * 4 + 2][jloc] = v.z;
          bT[c4 * 4 + 3][jloc] = v.w;
        }
      }
      __syncthreads();
#pragma unroll
      for (int c = 0; c < 32; ++c) {
        float4 av = *reinterpret_cast<const float4*>(&aT[c0 + c][4 * tp]);
        float4 bv = *reinterpret_cast<const float4*>(&bT[c][4 * to]);
        acc[0][0] = fmaf(av.x, bv.x, acc[0][0]); acc[0][1] = fmaf(av.x, bv.y, acc[0][1]);
        acc[0][2] = fmaf(av.x, bv.z, acc[0][2]); acc[0][3] = fmaf(av.x, bv.w, acc[0][3]);
        acc[1][0] = fmaf(av.y, bv.x, acc[1][0]); acc[1][1] = fmaf(av.y, bv.y, acc[1][1]);
        acc[1][2] = fmaf(av.y, bv.z, acc[1][2]); acc[1][3] = fmaf(av.y, bv.w, acc[1][3]);
        acc[2][0] = fmaf(av.z, bv.x, acc[2][0]); acc[2][1] = fmaf(av.z, bv.y, acc[2][1]);
        acc[2][2] = fmaf(av.z, bv.z, acc[2][2]); acc[2][3] = fmaf(av.z, bv.w, acc[2][3]);
        acc[3][0] = fmaf(av.w, bv.x, acc[3][0]); acc[3][1] = fmaf(av.w, bv.y, acc[3][1]);
        acc[3][2] = fmaf(av.w, bv.z, acc[3][2]); acc[3][3] = fmaf(av.w, bv.w, acc[3][3]);
      }
    }
    // epilogue: scale exactly as ref (/scale then *t1), write logit,
    // update both running argmaxes with the exact gumbel stream
#pragma unroll
    for (int ii = 0; ii < 4; ++ii) {
      int p = p0 + 4 * tp + ii;
      int jb = jt * 64 + 4 * to;
      float4 lv;
      lv.x = acc[ii][0] / LOGIT_SCALE_F * t1;
      lv.y = acc[ii][1] / LOGIT_SCALE_F * t1;
      lv.z = acc[ii][2] / LOGIT_SCALE_F * t1;
      lv.w = acc[ii][3] / LOGIT_SCALE_F * t1;
      *reinterpret_cast<float4*>(logit_out + (size_t)p * KCB + jb) = lv;
      float vals[4] = {lv.x, lv.y, lv.z, lv.w};
#pragma unroll
      for (int jj = 0; jj < 4; ++jj) {
        int jgl = jb + jj;
        float val = vals[jj];
        if (val > Lv[ii]) { Lv[ii] = val; Li[ii] = jgl; }  // j ascending -> first-wins
        uint32_t b0, b1;
        threefry_0_42(0u, (uint32_t)p * (uint32_t)KCB + (uint32_t)jgl, b0, b1);
        float s = val + gumbel_from_bits(b0 ^ b1);
        if (s > Sv[ii]) { Sv[ii] = s; Si[ii] = jgl; }
      }
    }
  }

  // in-wave reduce: lanes {tp, tp+16, tp+32, tp+48} share pixel rows
  {
    const int lane = tid & 63;
    const int wvid = tid >> 6;  // wave 0..3
#pragma unroll
    for (int ii = 0; ii < 4; ++ii) {
      float v = Lv[ii]; int idx = Li[ii];
      float s = Sv[ii]; int sidx = Si[ii];
#pragma unroll
      for (int m = 16; m <= 32; m <<= 1) {
        float v2 = __shfl_xor(v, m); int i2 = __shfl_xor(idx, m);
        if (v2 > v || (v2 == v && i2 < idx)) { v = v2; idx = i2; }
        float s2 = __shfl_xor(s, m); int j2 = __shfl_xor(sidx, m);
        if (s2 > s || (s2 == s && j2 < sidx)) { s = s2; sidx = j2; }
      }
      if (lane < 16) {
        int r = 4 * tp + ii;
        wLv[r][wvid] = v; wLi[r][wvid] = idx;
        wSv[r][wvid] = s; wSi[r][wvid] = sidx;
      }
    }
  }
  __syncthreads();
  if (tid < 64) {
    int r = tid;
    float bv = wLv[r][0]; int bi = wLi[r][0];
    float sv = wSv[r][0]; int si = wSi[r][0];
#pragma unroll
    for (int t = 1; t < 4; ++t) {
      float v1 = wLv[r][t]; int i1 = wLi[r][t];
      if (v1 > bv || (v1 == bv && i1 < bi)) { bv = v1; bi = i1; }
      float v2 = wSv[r][t]; int i2 = wSi[r][t];
      if (v2 > sv || (v2 == sv && i2 < si)) { sv = v2; si = i2; }
    }
    code_out[p0 + r] = (float)bi;
    sIdx[r] = si;
  }
  __syncthreads();

  // quantized[n][d][hw] = v[idx[p]][d]; lanes = 64 consecutive pixels
  {
    int l = tid & 63, dg = tid >> 6;
    int p = p0 + l;
    int n = p >> 12, hw = p & 4095;
    int jv = sIdx[l];
    const float* vrow = vm + (size_t)jv * COUT;
    float* qb = quant_out + (size_t)n * (COUT * HWSZ) + hw;
#pragma unroll
    for (int it = 0; it < 48; ++it) {
      int d = it * 4 + dg;
      qb[(size_t)d * HWSZ] = vrow[d];
    }
  }
}

// ---------------------------------------------------------------------------
extern "C" void kernel_launch(void* const* d_in, const int* in_sizes, int n_in,
                              void* d_out, int out_size, void* d_ws, size_t ws_size,
                              hipStream_t stream) {
  (void)in_sizes; (void)n_in; (void)out_size; (void)ws_size;
  const float* latent   = (const float*)d_in[0];
  const float* codebook = (const float*)d_in[1];
  const float* wq       = (const float*)d_in[2];
  const float* wk       = (const float*)d_in[3];
  const float* wv       = (const float*)d_in[4];
  const float* t1       = (const float*)d_in[5];
  // d_in[6] = temperature (int, ==1): positive scalar, cannot change outputs

  float* ws = (float*)d_ws;
  float* km = ws;               // 196,608 floats
  float* vm = ws + 196608;      // 196,608 floats  (total ws use: 1.57 MB)

  float* quant = (float*)d_out;          // 6,291,456
  float* code  = quant + 6291456;        //    32,768
  float* logit = code + 32768;           // 33,554,432 (cols 832..1023 stage q)

  kv_kernel<<<dim3(KCB), dim3(192), 0, stream>>>(codebook, wk, wv, km, vm);
  q_kernel<<<dim3(NPIX / 64, CIN / 64), dim3(256), 0, stream>>>(latent, wq, logit);
  logit_kernel<<<dim3(NPIX / 64), dim3(256), 0, stream>>>(km, vm, t1, logit, code, quant);
}